// Round 10
// baseline (169.564 us; speedup 1.0000x reference)
//
#include <hip/hip_runtime.h>

#define N_NODES 100000
#define N_EDGES 1600000
#define D_IN    128
#define D_OUT   64

// Bucket scheme: nodes grouped into buckets of G; per-bucket edge lists with
// fixed capacity CAP (avg fill 3840, binomial sd ~62 -> 6144 is ~37 sigma).
#define G     240
#define NBKT  ((N_NODES + G - 1) / G)          // 417
#define CAP   6144
#define EPB   2048                              // edges per partition block
#define PBLK  ((N_EDGES + EPB - 1) / EPB)       // 782
#define GBLK  ((N_NODES + 63) / 64)             // 1563 gemm blocks

// Wt LDS row stride (shorts). 136 = 68 dwords = 4 mod 32 banks: per-wave
// b128 B-frag reads spread 8 lanes per 4-bank group = intrinsic minimum
// (1KB / 128B-per-phase = 8 phases). Stride 128 (= 0 mod 32) put 16 lanes
// on one group -> 16 phases, the 1.59e7 SQ_LDS_BANK_CONFLICT of round 9.
#define WSTR  136

typedef __attribute__((ext_vector_type(8))) short bf16x8;
typedef __attribute__((ext_vector_type(4))) float f32x4;

// fp32 <-> bf16 helpers (RNE)
__device__ __forceinline__ unsigned short f2bf(float f) {
    union { float f; unsigned u; } v; v.f = f;
    const unsigned r = v.u + 0x7FFFu + ((v.u >> 16) & 1u);
    return (unsigned short)(r >> 16);
}
__device__ __forceinline__ float bf2f(unsigned short s) {
    union { unsigned u; float f; } v; v.u = ((unsigned)s) << 16;
    return v.f;
}

// ---------------------------------------------------------------------------
// Fused gemm + partition (block-range split; data-independent phases on
// disjoint resources). Blocks [0,PBLK): partition; [PBLK,PBLK+GBLK): gemm.
// LDS union: partition 22.5 KB | gemm 17.4 KB -> 7 blocks/CU.
// ---------------------------------------------------------------------------
__global__ __launch_bounds__(256) void fused_gp_kernel(const float* __restrict__ x,
                                                       const float* __restrict__ W,
                                                       unsigned short* __restrict__ hb,
                                                       const int* __restrict__ ei,
                                                       int* __restrict__ gcur,
                                                       int* __restrict__ ebuf) {
    __shared__ int smem[1536 + 2 * EPB];   // 22528 B (>= gemm's 17408 B)

    const int tid = threadIdx.x;

    if (blockIdx.x < PBLK) {
        // ----------------- partition path (restage + precomputed gdst) ------
        int* cnt   = smem;            // [512]
        int* sA    = smem + 512;      // [512]
        int* gbase = smem + 1024;     // [512]
        int* stage = smem + 1536;     // [EPB]
        int* gdst  = smem + 1536 + EPB;

        cnt[tid] = 0; cnt[tid + 256] = 0;
        __syncthreads();

        const int e0   = blockIdx.x * EPB;
        const int ecnt = min(EPB, N_EDGES - e0);

        int pk[8], meta[8];
        #pragma unroll
        for (int i = 0; i < 8; ++i) {
            const int l = tid + i * 256;
            meta[i] = -1;
            if (l < ecnt) {
                const int e   = e0 + l;
                const int src = ei[e];
                const int dst = ei[N_EDGES + e];
                const int b   = dst / G;
                const int dl  = dst - b * G;
                pk[i] = src | (dl << 17);
                const int r = atomicAdd(&cnt[b], 1);   // LDS atomic
                meta[i] = b | (r << 9);                // b:9b, r<2048:11b
            }
        }
        __syncthreads();

        sA[tid] = cnt[tid]; sA[tid + 256] = cnt[tid + 256];
        __syncthreads();
        for (int off = 1; off < 512; off <<= 1) {
            const int a0 = (tid >= off) ? sA[tid - off] : 0;
            const int a1 = sA[tid + 256 - off];
            __syncthreads();
            sA[tid] += a0; sA[tid + 256] += a1;
            __syncthreads();
        }

        for (int b = tid; b < NBKT; b += 256) {
            const int c = cnt[b];
            if (c > 0) gbase[b] = atomicAdd(&gcur[b], c);  // 1 dev atomic/bkt
        }
        __syncthreads();

        #pragma unroll
        for (int i = 0; i < 8; ++i) {
            if (meta[i] >= 0) {
                const int b    = meta[i] & 511;
                const int r    = meta[i] >> 9;
                const int spos = (sA[b] - cnt[b]) + r;
                const int g    = gbase[b] + r;
                stage[spos] = pk[i];
                gdst[spos]  = (g < CAP) ? b * CAP + g : -1;
            }
        }
        __syncthreads();

        #pragma unroll
        for (int i = 0; i < 8; ++i) {
            const int idx = tid + i * 256;
            if (idx < ecnt) {
                const int pos = gdst[idx];
                if (pos >= 0) ebuf[pos] = stage[idx];
            }
        }
    } else {
        // ----------------- gemm path (bf16 MFMA, padded W^T in LDS) ---------
        unsigned short* Wt = reinterpret_cast<unsigned short*>(smem);
        for (int i = tid; i < D_IN * D_OUT; i += 256) {
            const int k = i >> 6;                      // W is [k][f] row-major
            const int f = i & 63;
            Wt[f * WSTR + k] = f2bf(W[i]);
        }
        __syncthreads();

        const int wave = tid >> 6;
        const int lane = tid & 63;
        const int m    = lane & 15;
        const int quad = lane >> 4;
        const int n0   = (blockIdx.x - PBLK) * 64 + wave * 16;

        bf16x8 bfrag[4][4];
        #pragma unroll
        for (int ft = 0; ft < 4; ++ft)
            #pragma unroll
            for (int ks = 0; ks < 4; ++ks)
                bfrag[ft][ks] = *reinterpret_cast<const bf16x8*>(
                    &Wt[(ft * 16 + m) * WSTR + ks * 32 + quad * 8]);

        const int nodeA = min(n0 + m, N_NODES - 1);
        const float* xr = x + (size_t)nodeA * D_IN;
        bf16x8 afrag[4];
        #pragma unroll
        for (int ks = 0; ks < 4; ++ks) {
            const float4 u = *reinterpret_cast<const float4*>(xr + ks * 32 + quad * 8);
            const float4 v = *reinterpret_cast<const float4*>(xr + ks * 32 + quad * 8 + 4);
            bf16x8 a;
            a[0] = (short)f2bf(u.x); a[1] = (short)f2bf(u.y);
            a[2] = (short)f2bf(u.z); a[3] = (short)f2bf(u.w);
            a[4] = (short)f2bf(v.x); a[5] = (short)f2bf(v.y);
            a[6] = (short)f2bf(v.z); a[7] = (short)f2bf(v.w);
            afrag[ks] = a;
        }

        f32x4 acc[4];
        #pragma unroll
        for (int ft = 0; ft < 4; ++ft) { acc[ft][0]=0.f; acc[ft][1]=0.f; acc[ft][2]=0.f; acc[ft][3]=0.f; }

        #pragma unroll
        for (int ks = 0; ks < 4; ++ks)
            #pragma unroll
            for (int ft = 0; ft < 4; ++ft)
                acc[ft] = __builtin_amdgcn_mfma_f32_16x16x32_bf16(
                    afrag[ks], bfrag[ft][ks], acc[ft], 0, 0, 0);

        #pragma unroll
        for (int r = 0; r < 4; ++r) {
            const int node = n0 + quad * 4 + r;
            if (node < N_NODES) {
                #pragma unroll
                for (int ft = 0; ft < 4; ++ft)
                    hb[(size_t)node * D_OUT + ft * 16 + m] = f2bf(acc[ft][r]);
            }
        }
    }
}

// ---------------------------------------------------------------------------
// Accumulate v4: 2 blocks/bucket, local CSR in LDS, multi-row bf16 gather
// (4 rows/load-group, 4 groups in flight), fp32 register acc, shfl_xor
// reduce, fused bias+relu.
// ---------------------------------------------------------------------------
__global__ __launch_bounds__(512) void accumulate_kernel(const unsigned short* __restrict__ hb,
                                                         const int* __restrict__ gcur,
                                                         const int* __restrict__ ebuf,
                                                         const float* __restrict__ bias,
                                                         float* __restrict__ out) {
    __shared__ int srt[CAP];        // 24 KB
    __shared__ int cnt[256];
    __shared__ int scanb[256];
    __shared__ int start[G + 1];

    const int b   = blockIdx.x >> 1;
    const int p   = blockIdx.x & 1;
    const int tid = threadIdx.x;
    const int ecnt = min(gcur[b], CAP);

    if (tid < 256) cnt[tid] = 0;
    __syncthreads();

    int pk[8], rr[8];
    #pragma unroll
    for (int i = 0; i < 8; ++i) {
        const int idx = tid + i * 512;
        rr[i] = -1;
        if (idx < ecnt) {
            pk[i] = ebuf[(size_t)b * CAP + idx];
            rr[i] = atomicAdd(&cnt[pk[i] >> 17], 1);
        }
    }
    __syncthreads();

    if (tid < 256) scanb[tid] = cnt[tid];
    __syncthreads();
    for (int off = 1; off < 256; off <<= 1) {
        int v = 0;
        if (tid < 256 && tid >= off) v = scanb[tid - off];
        __syncthreads();
        if (tid < 256) scanb[tid] += v;
        __syncthreads();
    }
    if (tid <= G) start[tid] = (tid == 0) ? 0 : scanb[tid - 1];
    __syncthreads();

    #pragma unroll
    for (int i = 0; i < 8; ++i) {
        if (rr[i] >= 0) {
            const int dl = pk[i] >> 17;
            srt[start[dl] + rr[i]] = pk[i] & 0x1FFFF;
        }
    }
    __syncthreads();

    const int wave = tid >> 6;
    const int lane = tid & 63;
    const int sub  = lane >> 4;
    const int f4   = lane & 15;
    const ushort4* h4 = reinterpret_cast<const ushort4*>(hb);
    const float4 bv   = reinterpret_cast<const float4*>(bias)[f4];
    float4* o4 = reinterpret_cast<float4*>(out);

    const int r0 = p * (G / 2);
    for (int r = r0 + wave; r < r0 + G / 2; r += 8) {
        const int node = b * G + r;
        if (node >= N_NODES) break;
        const int s = start[r];
        const int e = start[r + 1];
        float4 acc = make_float4(0.f, 0.f, 0.f, 0.f);
        int j = s + sub;
        for (; j + 12 < e; j += 16) {
            const int s0 = srt[j], s1 = srt[j + 4], s2 = srt[j + 8], s3 = srt[j + 12];
            const ushort4 a0 = h4[(size_t)s0 * 16 + f4];
            const ushort4 a1 = h4[(size_t)s1 * 16 + f4];
            const ushort4 a2 = h4[(size_t)s2 * 16 + f4];
            const ushort4 a3 = h4[(size_t)s3 * 16 + f4];
            acc.x += bf2f(a0.x) + bf2f(a1.x) + bf2f(a2.x) + bf2f(a3.x);
            acc.y += bf2f(a0.y) + bf2f(a1.y) + bf2f(a2.y) + bf2f(a3.y);
            acc.z += bf2f(a0.z) + bf2f(a1.z) + bf2f(a2.z) + bf2f(a3.z);
            acc.w += bf2f(a0.w) + bf2f(a1.w) + bf2f(a2.w) + bf2f(a3.w);
        }
        for (; j < e; j += 4) {
            const ushort4 a = h4[(size_t)srt[j] * 16 + f4];
            acc.x += bf2f(a.x); acc.y += bf2f(a.y);
            acc.z += bf2f(a.z); acc.w += bf2f(a.w);
        }
        #pragma unroll
        for (int mm = 16; mm <= 32; mm <<= 1) {
            acc.x += __shfl_xor(acc.x, mm, 64);
            acc.y += __shfl_xor(acc.y, mm, 64);
            acc.z += __shfl_xor(acc.z, mm, 64);
            acc.w += __shfl_xor(acc.w, mm, 64);
        }
        if (sub == 0) {
            float4 o;
            o.x = fmaxf(acc.x + bv.x, 0.f);
            o.y = fmaxf(acc.y + bv.y, 0.f);
            o.z = fmaxf(acc.z + bv.z, 0.f);
            o.w = fmaxf(acc.w + bv.w, 0.f);
            o4[(size_t)node * 16 + f4] = o;
        }
    }
}

// ---------------------------------------------------------------------------
// Fallback path (standalone gemm + atomic scatter) if ws too small
// ---------------------------------------------------------------------------
__global__ __launch_bounds__(256) void gemm_fallback_kernel(const float* __restrict__ x,
                                                            const float* __restrict__ W,
                                                            unsigned short* __restrict__ hb) {
    __shared__ unsigned short Wt[D_OUT * WSTR];
    const int tid = threadIdx.x;
    for (int i = tid; i < D_IN * D_OUT; i += 256) {
        const int k = i >> 6;
        const int f = i & 63;
        Wt[f * WSTR + k] = f2bf(W[i]);
    }
    __syncthreads();

    const int wave = tid >> 6;
    const int lane = tid & 63;
    const int m    = lane & 15;
    const int quad = lane >> 4;
    const int n0   = blockIdx.x * 64 + wave * 16;

    bf16x8 bfrag[4][4];
    #pragma unroll
    for (int ft = 0; ft < 4; ++ft)
        #pragma unroll
        for (int ks = 0; ks < 4; ++ks)
            bfrag[ft][ks] = *reinterpret_cast<const bf16x8*>(
                &Wt[(ft * 16 + m) * WSTR + ks * 32 + quad * 8]);

    const int nodeA = min(n0 + m, N_NODES - 1);
    const float* xr = x + (size_t)nodeA * D_IN;
    bf16x8 afrag[4];
    #pragma unroll
    for (int ks = 0; ks < 4; ++ks) {
        const float4 u = *reinterpret_cast<const float4*>(xr + ks * 32 + quad * 8);
        const float4 v = *reinterpret_cast<const float4*>(xr + ks * 32 + quad * 8 + 4);
        bf16x8 a;
        a[0] = (short)f2bf(u.x); a[1] = (short)f2bf(u.y);
        a[2] = (short)f2bf(u.z); a[3] = (short)f2bf(u.w);
        a[4] = (short)f2bf(v.x); a[5] = (short)f2bf(v.y);
        a[6] = (short)f2bf(v.z); a[7] = (short)f2bf(v.w);
        afrag[ks] = a;
    }

    f32x4 acc[4];
    #pragma unroll
    for (int ft = 0; ft < 4; ++ft) { acc[ft][0]=0.f; acc[ft][1]=0.f; acc[ft][2]=0.f; acc[ft][3]=0.f; }

    #pragma unroll
    for (int ks = 0; ks < 4; ++ks)
        #pragma unroll
        for (int ft = 0; ft < 4; ++ft)
            acc[ft] = __builtin_amdgcn_mfma_f32_16x16x32_bf16(
                afrag[ks], bfrag[ft][ks], acc[ft], 0, 0, 0);

    #pragma unroll
    for (int r = 0; r < 4; ++r) {
        const int node = n0 + quad * 4 + r;
        if (node < N_NODES) {
            #pragma unroll
            for (int ft = 0; ft < 4; ++ft)
                hb[(size_t)node * D_OUT + ft * 16 + m] = f2bf(acc[ft][r]);
        }
    }
}

__global__ void init_bias_kernel(float* __restrict__ out, const float* __restrict__ b) {
    int i = blockIdx.x * blockDim.x + threadIdx.x;
    const int total4 = N_NODES * (D_OUT / 4);
    if (i < total4) {
        int f4 = i & (D_OUT / 4 - 1);
        reinterpret_cast<float4*>(out)[i] = reinterpret_cast<const float4*>(b)[f4];
    }
}

__global__ void scatter_kernel(const unsigned short* __restrict__ hb, const int* __restrict__ ei,
                               float* __restrict__ out) {
    const long long t = (long long)blockIdx.x * blockDim.x + threadIdx.x;
    const int e = (int)(t >> 6);
    const int f = (int)(t & 63);
    if (e < N_EDGES) {
        atomicAdd(out + (size_t)ei[N_EDGES + e] * D_OUT + f,
                  bf2f(hb[(size_t)ei[e] * D_OUT + f]));
    }
}

__global__ void relu_kernel(float* __restrict__ out) {
    int i = blockIdx.x * blockDim.x + threadIdx.x;
    const int total4 = N_NODES * (D_OUT / 4);
    if (i < total4) {
        float4 v = reinterpret_cast<float4*>(out)[i];
        v.x = fmaxf(v.x, 0.f); v.y = fmaxf(v.y, 0.f);
        v.z = fmaxf(v.z, 0.f); v.w = fmaxf(v.w, 0.f);
        reinterpret_cast<float4*>(out)[i] = v;
    }
}

// ---------------------------------------------------------------------------
extern "C" void kernel_launch(void* const* d_in, const int* in_sizes, int n_in,
                              void* d_out, int out_size, void* d_ws, size_t ws_size,
                              hipStream_t stream) {
    const float* x  = (const float*)d_in[0];
    const int*   ei = (const int*)d_in[1];
    const float* W  = (const float*)d_in[2];
    const float* b  = (const float*)d_in[3];
    float* out = (float*)d_out;
    char*  ws  = (char*)d_ws;

    size_t off = 0;
    auto take = [&](size_t bytes) { size_t p = off; off = (off + bytes + 255) & ~255ULL; return p; };
    const size_t o_h    = take((size_t)N_NODES * D_OUT * sizeof(unsigned short)); // 12.8 MB
    const size_t o_gcur = take((size_t)NBKT * sizeof(int));
    const size_t o_ebuf = take((size_t)NBKT * CAP * sizeof(int));                 // 10.25 MB
    const size_t needed = off;

    unsigned short* hb = (unsigned short*)(ws + o_h);

    if (needed <= ws_size) {
        int* gcur = (int*)(ws + o_gcur);
        int* ebuf = (int*)(ws + o_ebuf);
        hipMemsetAsync(gcur, 0, (size_t)NBKT * sizeof(int), stream);
        fused_gp_kernel<<<PBLK + GBLK, 256, 0, stream>>>(x, W, hb, ei, gcur, ebuf);
        accumulate_kernel<<<NBKT * 2, 512, 0, stream>>>(hb, gcur, ebuf, b, out);
    } else {
        gemm_fallback_kernel<<<GBLK, 256, 0, stream>>>(x, W, hb);
        const int total4 = N_NODES * (D_OUT / 4);
        init_bias_kernel<<<(total4 + 255) / 256, 256, 0, stream>>>(out, b);
        const long long threads = (long long)N_EDGES * 64;
        scatter_kernel<<<(int)((threads + 255) / 256), 256, 0, stream>>>(hb, ei, out);
        relu_kernel<<<(total4 + 255) / 256, 256, 0, stream>>>(out);
    }
}

// Round 11
// 148.485 us; speedup vs baseline: 1.1420x; 1.1420x over previous
//
#include <hip/hip_runtime.h>

#define N_NODES 100000
#define N_EDGES 1600000
#define D_IN    128
#define D_OUT   64

// Bucket scheme: nodes grouped into buckets of G; per-bucket edge lists with
// fixed capacity CAP (avg fill 3840, binomial sd ~62 -> 6144 is ~37 sigma).
#define G     240
#define NBKT  ((N_NODES + G - 1) / G)          // 417
#define CAP   6144
#define EPB   8192                              // edges per partition block
#define PBLK  ((N_EDGES + EPB - 1) / EPB)       // 196
#define GBLK  ((N_NODES + 127) / 128)           // 782 gemm blocks (128 nodes ea)

// Wt LDS row stride (shorts): 136 = 4 mod 32 banks -> conflict-minimal b128
// reads (verified round 10: conflicts 1.59e7 -> 2.3e6).
#define WSTR  136

typedef __attribute__((ext_vector_type(8))) short bf16x8;
typedef __attribute__((ext_vector_type(4))) float f32x4;

// fp32 <-> bf16 helpers (RNE)
__device__ __forceinline__ unsigned short f2bf(float f) {
    union { float f; unsigned u; } v; v.f = f;
    const unsigned r = v.u + 0x7FFFu + ((v.u >> 16) & 1u);
    return (unsigned short)(r >> 16);
}
__device__ __forceinline__ float bf2f(unsigned short s) {
    union { unsigned u; float f; } v; v.u = ((unsigned)s) << 16;
    return v.f;
}

// ---------------------------------------------------------------------------
// Fused gemm + partition, 512-thread blocks.
// Blocks [0,PBLK): partition EPB=8192 edges -> runs of ~19.6 edges per
// (block,bucket): the ebuf writeout line-scatter (the round-9/10 binder,
// ~350K 64B-lines at the ~18G lines/s scattered-store ceiling) halves.
// bstage[] (u16 bucket per slot) + adjusted gbase replaces gdst: LDS total
// 54KB < 64KB static limit -> 2 blocks/CU.
// Blocks [PBLK,PBLK+GBLK): bf16 MFMA gemm, 8 waves x 16 nodes = 128/block.
// ---------------------------------------------------------------------------
__global__ __launch_bounds__(512) void fused_gp_kernel(const float* __restrict__ x,
                                                       const float* __restrict__ W,
                                                       unsigned short* __restrict__ hb,
                                                       const int* __restrict__ ei,
                                                       int* __restrict__ gcur,
                                                       int* __restrict__ ebuf) {
    __shared__ int smem[1536 + EPB + EPB / 2];   // 55296 B

    const int tid = threadIdx.x;

    if (blockIdx.x < PBLK) {
        // ----------------- partition path -----------------------------------
        int* cnt   = smem;            // [512]
        int* sA    = smem + 512;      // [512] inclusive scan
        int* gbase = smem + 1024;     // [512] adjusted global base
        int* stage = smem + 1536;     // [EPB] packed edges, bucket-grouped
        unsigned short* bstage = (unsigned short*)(smem + 1536 + EPB); // [EPB]

        cnt[tid] = 0;
        __syncthreads();

        const int e0   = blockIdx.x * EPB;
        const int ecnt = min(EPB, N_EDGES - e0);

        int pk[16], meta[16];
        #pragma unroll
        for (int i = 0; i < 16; ++i) {
            const int l = tid + i * 512;
            meta[i] = -1;
            if (l < ecnt) {
                const int e   = e0 + l;
                const int src = ei[e];
                const int dst = ei[N_EDGES + e];
                const int b   = dst / G;
                const int dl  = dst - b * G;
                pk[i] = src | (dl << 17);
                const int r = atomicAdd(&cnt[b], 1);   // LDS atomic
                meta[i] = b | (r << 9);                // b:9b, r<8192:13b
            }
        }
        __syncthreads();

        // Hillis-Steele inclusive scan over 512 entries, 512 threads
        sA[tid] = cnt[tid];
        __syncthreads();
        for (int off = 1; off < 512; off <<= 1) {
            const int v = (tid >= off) ? sA[tid - off] : 0;
            __syncthreads();
            sA[tid] += v;
            __syncthreads();
        }

        // one device atomic per non-empty bucket; store base adjusted by the
        // bucket's exclusive start so writeout is gbase[b] + idx
        if (tid < NBKT) {
            const int c  = cnt[tid];
            const int ex = sA[tid] - c;
            if (c > 0) gbase[tid] = atomicAdd(&gcur[tid], c) - ex;
        }
        __syncthreads();

        // restage bucket-grouped: slot = excl[b] + r; record bucket id
        #pragma unroll
        for (int i = 0; i < 16; ++i) {
            if (meta[i] >= 0) {
                const int b    = meta[i] & 511;
                const int r    = meta[i] >> 9;
                const int spos = (sA[b] - cnt[b]) + r;
                stage[spos]  = pk[i];
                bstage[spos] = (unsigned short)b;
            }
        }
        __syncthreads();

        // writeout: consecutive idx -> consecutive global slots within runs
        #pragma unroll
        for (int i = 0; i < 16; ++i) {
            const int idx = tid + i * 512;
            if (idx < ecnt) {
                const int b   = bstage[idx];
                const int pib = gbase[b] + idx;     // position in bucket
                if ((unsigned)pib < CAP) ebuf[b * CAP + pib] = stage[idx];
            }
        }
    } else {
        // ----------------- gemm path (bf16 MFMA, padded W^T in LDS) ---------
        unsigned short* Wt = reinterpret_cast<unsigned short*>(smem);
        for (int i = tid; i < D_IN * D_OUT; i += 512) {
            const int k = i >> 6;                      // W is [k][f] row-major
            const int f = i & 63;
            Wt[f * WSTR + k] = f2bf(W[i]);
        }
        __syncthreads();

        const int wave = tid >> 6;                     // 0..7
        const int lane = tid & 63;
        const int m    = lane & 15;
        const int quad = lane >> 4;
        const int n0   = (blockIdx.x - PBLK) * 128 + wave * 16;

        bf16x8 bfrag[4][4];
        #pragma unroll
        for (int ft = 0; ft < 4; ++ft)
            #pragma unroll
            for (int ks = 0; ks < 4; ++ks)
                bfrag[ft][ks] = *reinterpret_cast<const bf16x8*>(
                    &Wt[(ft * 16 + m) * WSTR + ks * 32 + quad * 8]);

        const int nodeA = min(n0 + m, N_NODES - 1);
        const float* xr = x + (size_t)nodeA * D_IN;
        bf16x8 afrag[4];
        #pragma unroll
        for (int ks = 0; ks < 4; ++ks) {
            const float4 u = *reinterpret_cast<const float4*>(xr + ks * 32 + quad * 8);
            const float4 v = *reinterpret_cast<const float4*>(xr + ks * 32 + quad * 8 + 4);
            bf16x8 a;
            a[0] = (short)f2bf(u.x); a[1] = (short)f2bf(u.y);
            a[2] = (short)f2bf(u.z); a[3] = (short)f2bf(u.w);
            a[4] = (short)f2bf(v.x); a[5] = (short)f2bf(v.y);
            a[6] = (short)f2bf(v.z); a[7] = (short)f2bf(v.w);
            afrag[ks] = a;
        }

        f32x4 acc[4];
        #pragma unroll
        for (int ft = 0; ft < 4; ++ft) { acc[ft][0]=0.f; acc[ft][1]=0.f; acc[ft][2]=0.f; acc[ft][3]=0.f; }

        #pragma unroll
        for (int ks = 0; ks < 4; ++ks)
            #pragma unroll
            for (int ft = 0; ft < 4; ++ft)
                acc[ft] = __builtin_amdgcn_mfma_f32_16x16x32_bf16(
                    afrag[ks], bfrag[ft][ks], acc[ft], 0, 0, 0);

        #pragma unroll
        for (int r = 0; r < 4; ++r) {
            const int node = n0 + quad * 4 + r;
            if (node < N_NODES) {
                #pragma unroll
                for (int ft = 0; ft < 4; ++ft)
                    hb[(size_t)node * D_OUT + ft * 16 + m] = f2bf(acc[ft][r]);
            }
        }
    }
}

// ---------------------------------------------------------------------------
// Accumulate v4: 2 blocks/bucket, local CSR in LDS, multi-row bf16 gather
// (4 rows/load-group, 4 groups in flight), fp32 register acc, shfl_xor
// reduce, fused bias+relu. Within ~12% of the measured cache-service
// ceiling for this traffic -- unchanged.
// ---------------------------------------------------------------------------
__global__ __launch_bounds__(512) void accumulate_kernel(const unsigned short* __restrict__ hb,
                                                         const int* __restrict__ gcur,
                                                         const int* __restrict__ ebuf,
                                                         const float* __restrict__ bias,
                                                         float* __restrict__ out) {
    __shared__ int srt[CAP];        // 24 KB
    __shared__ int cnt[256];
    __shared__ int scanb[256];
    __shared__ int start[G + 1];

    const int b   = blockIdx.x >> 1;
    const int p   = blockIdx.x & 1;
    const int tid = threadIdx.x;
    const int ecnt = min(gcur[b], CAP);

    if (tid < 256) cnt[tid] = 0;
    __syncthreads();

    int pk[8], rr[8];
    #pragma unroll
    for (int i = 0; i < 8; ++i) {
        const int idx = tid + i * 512;
        rr[i] = -1;
        if (idx < ecnt) {
            pk[i] = ebuf[(size_t)b * CAP + idx];
            rr[i] = atomicAdd(&cnt[pk[i] >> 17], 1);
        }
    }
    __syncthreads();

    if (tid < 256) scanb[tid] = cnt[tid];
    __syncthreads();
    for (int off = 1; off < 256; off <<= 1) {
        int v = 0;
        if (tid < 256 && tid >= off) v = scanb[tid - off];
        __syncthreads();
        if (tid < 256) scanb[tid] += v;
        __syncthreads();
    }
    if (tid <= G) start[tid] = (tid == 0) ? 0 : scanb[tid - 1];
    __syncthreads();

    #pragma unroll
    for (int i = 0; i < 8; ++i) {
        if (rr[i] >= 0) {
            const int dl = pk[i] >> 17;
            srt[start[dl] + rr[i]] = pk[i] & 0x1FFFF;
        }
    }
    __syncthreads();

    const int wave = tid >> 6;
    const int lane = tid & 63;
    const int sub  = lane >> 4;
    const int f4   = lane & 15;
    const ushort4* h4 = reinterpret_cast<const ushort4*>(hb);
    const float4 bv   = reinterpret_cast<const float4*>(bias)[f4];
    float4* o4 = reinterpret_cast<float4*>(out);

    const int r0 = p * (G / 2);
    for (int r = r0 + wave; r < r0 + G / 2; r += 8) {
        const int node = b * G + r;
        if (node >= N_NODES) break;
        const int s = start[r];
        const int e = start[r + 1];
        float4 acc = make_float4(0.f, 0.f, 0.f, 0.f);
        int j = s + sub;
        for (; j + 12 < e; j += 16) {
            const int s0 = srt[j], s1 = srt[j + 4], s2 = srt[j + 8], s3 = srt[j + 12];
            const ushort4 a0 = h4[(size_t)s0 * 16 + f4];
            const ushort4 a1 = h4[(size_t)s1 * 16 + f4];
            const ushort4 a2 = h4[(size_t)s2 * 16 + f4];
            const ushort4 a3 = h4[(size_t)s3 * 16 + f4];
            acc.x += bf2f(a0.x) + bf2f(a1.x) + bf2f(a2.x) + bf2f(a3.x);
            acc.y += bf2f(a0.y) + bf2f(a1.y) + bf2f(a2.y) + bf2f(a3.y);
            acc.z += bf2f(a0.z) + bf2f(a1.z) + bf2f(a2.z) + bf2f(a3.z);
            acc.w += bf2f(a0.w) + bf2f(a1.w) + bf2f(a2.w) + bf2f(a3.w);
        }
        for (; j < e; j += 4) {
            const ushort4 a = h4[(size_t)srt[j] * 16 + f4];
            acc.x += bf2f(a.x); acc.y += bf2f(a.y);
            acc.z += bf2f(a.z); acc.w += bf2f(a.w);
        }
        #pragma unroll
        for (int mm = 16; mm <= 32; mm <<= 1) {
            acc.x += __shfl_xor(acc.x, mm, 64);
            acc.y += __shfl_xor(acc.y, mm, 64);
            acc.z += __shfl_xor(acc.z, mm, 64);
            acc.w += __shfl_xor(acc.w, mm, 64);
        }
        if (sub == 0) {
            float4 o;
            o.x = fmaxf(acc.x + bv.x, 0.f);
            o.y = fmaxf(acc.y + bv.y, 0.f);
            o.z = fmaxf(acc.z + bv.z, 0.f);
            o.w = fmaxf(acc.w + bv.w, 0.f);
            o4[(size_t)node * 16 + f4] = o;
        }
    }
}

// ---------------------------------------------------------------------------
// Fallback path (standalone gemm + atomic scatter) if ws too small
// ---------------------------------------------------------------------------
__global__ __launch_bounds__(256) void gemm_fallback_kernel(const float* __restrict__ x,
                                                            const float* __restrict__ W,
                                                            unsigned short* __restrict__ hb) {
    __shared__ unsigned short Wt[D_OUT * WSTR];
    const int tid = threadIdx.x;
    for (int i = tid; i < D_IN * D_OUT; i += 256) {
        const int k = i >> 6;
        const int f = i & 63;
        Wt[f * WSTR + k] = f2bf(W[i]);
    }
    __syncthreads();

    const int wave = tid >> 6;
    const int lane = tid & 63;
    const int m    = lane & 15;
    const int quad = lane >> 4;
    const int n0   = blockIdx.x * 64 + wave * 16;

    bf16x8 bfrag[4][4];
    #pragma unroll
    for (int ft = 0; ft < 4; ++ft)
        #pragma unroll
        for (int ks = 0; ks < 4; ++ks)
            bfrag[ft][ks] = *reinterpret_cast<const bf16x8*>(
                &Wt[(ft * 16 + m) * WSTR + ks * 32 + quad * 8]);

    const int nodeA = min(n0 + m, N_NODES - 1);
    const float* xr = x + (size_t)nodeA * D_IN;
    bf16x8 afrag[4];
    #pragma unroll
    for (int ks = 0; ks < 4; ++ks) {
        const float4 u = *reinterpret_cast<const float4*>(xr + ks * 32 + quad * 8);
        const float4 v = *reinterpret_cast<const float4*>(xr + ks * 32 + quad * 8 + 4);
        bf16x8 a;
        a[0] = (short)f2bf(u.x); a[1] = (short)f2bf(u.y);
        a[2] = (short)f2bf(u.z); a[3] = (short)f2bf(u.w);
        a[4] = (short)f2bf(v.x); a[5] = (short)f2bf(v.y);
        a[6] = (short)f2bf(v.z); a[7] = (short)f2bf(v.w);
        afrag[ks] = a;
    }

    f32x4 acc[4];
    #pragma unroll
    for (int ft = 0; ft < 4; ++ft) { acc[ft][0]=0.f; acc[ft][1]=0.f; acc[ft][2]=0.f; acc[ft][3]=0.f; }

    #pragma unroll
    for (int ks = 0; ks < 4; ++ks)
        #pragma unroll
        for (int ft = 0; ft < 4; ++ft)
            acc[ft] = __builtin_amdgcn_mfma_f32_16x16x32_bf16(
                afrag[ks], bfrag[ft][ks], acc[ft], 0, 0, 0);

    #pragma unroll
    for (int r = 0; r < 4; ++r) {
        const int node = n0 + quad * 4 + r;
        if (node < N_NODES) {
            #pragma unroll
            for (int ft = 0; ft < 4; ++ft)
                hb[(size_t)node * D_OUT + ft * 16 + m] = f2bf(acc[ft][r]);
        }
    }
}

__global__ void init_bias_kernel(float* __restrict__ out, const float* __restrict__ b) {
    int i = blockIdx.x * blockDim.x + threadIdx.x;
    const int total4 = N_NODES * (D_OUT / 4);
    if (i < total4) {
        int f4 = i & (D_OUT / 4 - 1);
        reinterpret_cast<float4*>(out)[i] = reinterpret_cast<const float4*>(b)[f4];
    }
}

__global__ void scatter_kernel(const unsigned short* __restrict__ hb, const int* __restrict__ ei,
                               float* __restrict__ out) {
    const long long t = (long long)blockIdx.x * blockDim.x + threadIdx.x;
    const int e = (int)(t >> 6);
    const int f = (int)(t & 63);
    if (e < N_EDGES) {
        atomicAdd(out + (size_t)ei[N_EDGES + e] * D_OUT + f,
                  bf2f(hb[(size_t)ei[e] * D_OUT + f]));
    }
}

__global__ void relu_kernel(float* __restrict__ out) {
    int i = blockIdx.x * blockDim.x + threadIdx.x;
    const int total4 = N_NODES * (D_OUT / 4);
    if (i < total4) {
        float4 v = reinterpret_cast<float4*>(out)[i];
        v.x = fmaxf(v.x, 0.f); v.y = fmaxf(v.y, 0.f);
        v.z = fmaxf(v.z, 0.f); v.w = fmaxf(v.w, 0.f);
        reinterpret_cast<float4*>(out)[i] = v;
    }
}

// ---------------------------------------------------------------------------
extern "C" void kernel_launch(void* const* d_in, const int* in_sizes, int n_in,
                              void* d_out, int out_size, void* d_ws, size_t ws_size,
                              hipStream_t stream) {
    const float* x  = (const float*)d_in[0];
    const int*   ei = (const int*)d_in[1];
    const float* W  = (const float*)d_in[2];
    const float* b  = (const float*)d_in[3];
    float* out = (float*)d_out;
    char*  ws  = (char*)d_ws;

    size_t off = 0;
    auto take = [&](size_t bytes) { size_t p = off; off = (off + bytes + 255) & ~255ULL; return p; };
    const size_t o_h    = take((size_t)N_NODES * D_OUT * sizeof(unsigned short)); // 12.8 MB
    const size_t o_gcur = take((size_t)NBKT * sizeof(int));
    const size_t o_ebuf = take((size_t)NBKT * CAP * sizeof(int));                 // 10.25 MB
    const size_t needed = off;

    unsigned short* hb = (unsigned short*)(ws + o_h);

    if (needed <= ws_size) {
        int* gcur = (int*)(ws + o_gcur);
        int* ebuf = (int*)(ws + o_ebuf);
        hipMemsetAsync(gcur, 0, (size_t)NBKT * sizeof(int), stream);
        fused_gp_kernel<<<PBLK + GBLK, 512, 0, stream>>>(x, W, hb, ei, gcur, ebuf);
        accumulate_kernel<<<NBKT * 2, 512, 0, stream>>>(hb, gcur, ebuf, b, out);
    } else {
        gemm_fallback_kernel<<<(N_NODES + 63) / 64, 256, 0, stream>>>(x, W, hb);
        const int total4 = N_NODES * (D_OUT / 4);
        init_bias_kernel<<<(total4 + 255) / 256, 256, 0, stream>>>(out, b);
        const long long threads = (long long)N_EDGES * 64;
        scatter_kernel<<<(int)((threads + 255) / 256), 256, 0, stream>>>(hb, ei, out);
        relu_kernel<<<(total4 + 255) / 256, 256, 0, stream>>>(out);
    }
}

// Round 12
// 147.770 us; speedup vs baseline: 1.1475x; 1.0048x over previous
//
#include <hip/hip_runtime.h>

#define N_NODES 100000
#define N_EDGES 1600000
#define D_IN    128
#define D_OUT   64

// Bucket scheme: nodes grouped into buckets of G; per-bucket edge lists with
// fixed capacity CAP (avg fill 3840, binomial sd ~62 -> 6144 is ~37 sigma).
#define G     240
#define NBKT  ((N_NODES + G - 1) / G)          // 417
#define CAP   6144
#define EPB   8192                              // edges per partition block
#define PBLK  ((N_EDGES + EPB - 1) / EPB)       // 196
#define GBLK  ((N_NODES + 127) / 128)           // 782 gemm blocks (128 nodes ea)

// Wt LDS row stride (shorts): 136 = 4 mod 32 banks -> conflict-minimal b128
// reads (verified round 10: conflicts 1.59e7 -> 2.3e6).
#define WSTR  136

typedef __attribute__((ext_vector_type(8))) short bf16x8;
typedef __attribute__((ext_vector_type(4))) float f32x4;

// fp32 <-> bf16 helpers (RNE)
__device__ __forceinline__ unsigned short f2bf(float f) {
    union { float f; unsigned u; } v; v.f = f;
    const unsigned r = v.u + 0x7FFFu + ((v.u >> 16) & 1u);
    return (unsigned short)(r >> 16);
}
__device__ __forceinline__ float bf2f(unsigned short s) {
    union { unsigned u; float f; } v; v.u = ((unsigned)s) << 16;
    return v.f;
}

// ---------------------------------------------------------------------------
// Fused gemm + partition (unchanged from round 11 -- it delivered).
// Blocks [0,PBLK): partition EPB=8192 -> ~19.6-edge coalesced runs.
// Blocks [PBLK,PBLK+GBLK): bf16 MFMA gemm, 8 waves x 16 nodes.
// ---------------------------------------------------------------------------
__global__ __launch_bounds__(512) void fused_gp_kernel(const float* __restrict__ x,
                                                       const float* __restrict__ W,
                                                       unsigned short* __restrict__ hb,
                                                       const int* __restrict__ ei,
                                                       int* __restrict__ gcur,
                                                       int* __restrict__ ebuf) {
    __shared__ int smem[1536 + EPB + EPB / 2];   // 55296 B

    const int tid = threadIdx.x;

    if (blockIdx.x < PBLK) {
        // ----------------- partition path -----------------------------------
        int* cnt   = smem;            // [512]
        int* sA    = smem + 512;      // [512] inclusive scan
        int* gbase = smem + 1024;     // [512] adjusted global base
        int* stage = smem + 1536;     // [EPB] packed edges, bucket-grouped
        unsigned short* bstage = (unsigned short*)(smem + 1536 + EPB); // [EPB]

        cnt[tid] = 0;
        __syncthreads();

        const int e0   = blockIdx.x * EPB;
        const int ecnt = min(EPB, N_EDGES - e0);

        int pk[16], meta[16];
        #pragma unroll
        for (int i = 0; i < 16; ++i) {
            const int l = tid + i * 512;
            meta[i] = -1;
            if (l < ecnt) {
                const int e   = e0 + l;
                const int src = ei[e];
                const int dst = ei[N_EDGES + e];
                const int b   = dst / G;
                const int dl  = dst - b * G;
                pk[i] = src | (dl << 17);
                const int r = atomicAdd(&cnt[b], 1);   // LDS atomic
                meta[i] = b | (r << 9);                // b:9b, r<8192:13b
            }
        }
        __syncthreads();

        sA[tid] = cnt[tid];
        __syncthreads();
        for (int off = 1; off < 512; off <<= 1) {
            const int v = (tid >= off) ? sA[tid - off] : 0;
            __syncthreads();
            sA[tid] += v;
            __syncthreads();
        }

        if (tid < NBKT) {
            const int c  = cnt[tid];
            const int ex = sA[tid] - c;
            if (c > 0) gbase[tid] = atomicAdd(&gcur[tid], c) - ex;
        }
        __syncthreads();

        #pragma unroll
        for (int i = 0; i < 16; ++i) {
            if (meta[i] >= 0) {
                const int b    = meta[i] & 511;
                const int r    = meta[i] >> 9;
                const int spos = (sA[b] - cnt[b]) + r;
                stage[spos]  = pk[i];
                bstage[spos] = (unsigned short)b;
            }
        }
        __syncthreads();

        #pragma unroll
        for (int i = 0; i < 16; ++i) {
            const int idx = tid + i * 512;
            if (idx < ecnt) {
                const int b   = bstage[idx];
                const int pib = gbase[b] + idx;     // position in bucket
                if ((unsigned)pib < CAP) ebuf[b * CAP + pib] = stage[idx];
            }
        }
    } else {
        // ----------------- gemm path (bf16 MFMA, padded W^T in LDS) ---------
        unsigned short* Wt = reinterpret_cast<unsigned short*>(smem);
        for (int i = tid; i < D_IN * D_OUT; i += 512) {
            const int k = i >> 6;                      // W is [k][f] row-major
            const int f = i & 63;
            Wt[f * WSTR + k] = f2bf(W[i]);
        }
        __syncthreads();

        const int wave = tid >> 6;                     // 0..7
        const int lane = tid & 63;
        const int m    = lane & 15;
        const int quad = lane >> 4;
        const int n0   = (blockIdx.x - PBLK) * 128 + wave * 16;

        bf16x8 bfrag[4][4];
        #pragma unroll
        for (int ft = 0; ft < 4; ++ft)
            #pragma unroll
            for (int ks = 0; ks < 4; ++ks)
                bfrag[ft][ks] = *reinterpret_cast<const bf16x8*>(
                    &Wt[(ft * 16 + m) * WSTR + ks * 32 + quad * 8]);

        const int nodeA = min(n0 + m, N_NODES - 1);
        const float* xr = x + (size_t)nodeA * D_IN;
        bf16x8 afrag[4];
        #pragma unroll
        for (int ks = 0; ks < 4; ++ks) {
            const float4 u = *reinterpret_cast<const float4*>(xr + ks * 32 + quad * 8);
            const float4 v = *reinterpret_cast<const float4*>(xr + ks * 32 + quad * 8 + 4);
            bf16x8 a;
            a[0] = (short)f2bf(u.x); a[1] = (short)f2bf(u.y);
            a[2] = (short)f2bf(u.z); a[3] = (short)f2bf(u.w);
            a[4] = (short)f2bf(v.x); a[5] = (short)f2bf(v.y);
            a[6] = (short)f2bf(v.z); a[7] = (short)f2bf(v.w);
            afrag[ks] = a;
        }

        f32x4 acc[4];
        #pragma unroll
        for (int ft = 0; ft < 4; ++ft) { acc[ft][0]=0.f; acc[ft][1]=0.f; acc[ft][2]=0.f; acc[ft][3]=0.f; }

        #pragma unroll
        for (int ks = 0; ks < 4; ++ks)
            #pragma unroll
            for (int ft = 0; ft < 4; ++ft)
                acc[ft] = __builtin_amdgcn_mfma_f32_16x16x32_bf16(
                    afrag[ks], bfrag[ft][ks], acc[ft], 0, 0, 0);

        #pragma unroll
        for (int r = 0; r < 4; ++r) {
            const int node = n0 + quad * 4 + r;
            if (node < N_NODES) {
                #pragma unroll
                for (int ft = 0; ft < 4; ++ft)
                    hb[(size_t)node * D_OUT + ft * 16 + m] = f2bf(acc[ft][r]);
            }
        }
    }
}

// ---------------------------------------------------------------------------
// Accumulate v5: ONE 1024-thread block per bucket (was 2x512 duplicating the
// whole CSR build: 2x ebuf read, 2x hist atomics, 2x scan). Build once, then
// 16 waves gather 240 rows. 27KB LDS -> 2 blocks/CU = 32 waves (full).
// Also fixes latent coverage: loader now covers all CAP=6144 slots (the
// 512-thread version covered only 4096; max bucket ~4090 was ~1 sigma away
// from silent edge drops).
// ---------------------------------------------------------------------------
__global__ __launch_bounds__(1024) void accumulate_kernel(const unsigned short* __restrict__ hb,
                                                          const int* __restrict__ gcur,
                                                          const int* __restrict__ ebuf,
                                                          const float* __restrict__ bias,
                                                          float* __restrict__ out) {
    __shared__ int srt[CAP];        // 24 KB
    __shared__ int cnt[256];
    __shared__ int scanb[256];
    __shared__ int start[G + 1];

    const int b   = blockIdx.x;
    const int tid = threadIdx.x;
    const int ecnt = min(gcur[b], CAP);

    if (tid < 256) cnt[tid] = 0;
    __syncthreads();

    int pk[6], rr[6];
    #pragma unroll
    for (int i = 0; i < 6; ++i) {               // 6*1024 = 6144 = CAP
        const int idx = tid + i * 1024;
        rr[i] = -1;
        if (idx < ecnt) {
            pk[i] = ebuf[(size_t)b * CAP + idx];
            rr[i] = atomicAdd(&cnt[pk[i] >> 17], 1);
        }
    }
    __syncthreads();

    if (tid < 256) scanb[tid] = cnt[tid];
    __syncthreads();
    for (int off = 1; off < 256; off <<= 1) {
        int v = 0;
        if (tid < 256 && tid >= off) v = scanb[tid - off];
        __syncthreads();
        if (tid < 256) scanb[tid] += v;
        __syncthreads();
    }
    if (tid <= G) start[tid] = (tid == 0) ? 0 : scanb[tid - 1];
    __syncthreads();

    #pragma unroll
    for (int i = 0; i < 6; ++i) {
        if (rr[i] >= 0) {
            const int dl = pk[i] >> 17;
            srt[start[dl] + rr[i]] = pk[i] & 0x1FFFF;
        }
    }
    __syncthreads();

    const int wave = tid >> 6;                   // 0..15
    const int lane = tid & 63;
    const int sub  = lane >> 4;
    const int f4   = lane & 15;
    const ushort4* h4 = reinterpret_cast<const ushort4*>(hb);
    const float4 bv   = reinterpret_cast<const float4*>(bias)[f4];
    float4* o4 = reinterpret_cast<float4*>(out);

    for (int r = wave; r < G; r += 16) {
        const int node = b * G + r;
        if (node >= N_NODES) break;
        const int s = start[r];
        const int e = start[r + 1];
        float4 acc = make_float4(0.f, 0.f, 0.f, 0.f);
        int j = s + sub;
        for (; j + 12 < e; j += 16) {
            const int s0 = srt[j], s1 = srt[j + 4], s2 = srt[j + 8], s3 = srt[j + 12];
            const ushort4 a0 = h4[(size_t)s0 * 16 + f4];
            const ushort4 a1 = h4[(size_t)s1 * 16 + f4];
            const ushort4 a2 = h4[(size_t)s2 * 16 + f4];
            const ushort4 a3 = h4[(size_t)s3 * 16 + f4];
            acc.x += bf2f(a0.x) + bf2f(a1.x) + bf2f(a2.x) + bf2f(a3.x);
            acc.y += bf2f(a0.y) + bf2f(a1.y) + bf2f(a2.y) + bf2f(a3.y);
            acc.z += bf2f(a0.z) + bf2f(a1.z) + bf2f(a2.z) + bf2f(a3.z);
            acc.w += bf2f(a0.w) + bf2f(a1.w) + bf2f(a2.w) + bf2f(a3.w);
        }
        for (; j < e; j += 4) {
            const ushort4 a = h4[(size_t)srt[j] * 16 + f4];
            acc.x += bf2f(a.x); acc.y += bf2f(a.y);
            acc.z += bf2f(a.z); acc.w += bf2f(a.w);
        }
        #pragma unroll
        for (int mm = 16; mm <= 32; mm <<= 1) {
            acc.x += __shfl_xor(acc.x, mm, 64);
            acc.y += __shfl_xor(acc.y, mm, 64);
            acc.z += __shfl_xor(acc.z, mm, 64);
            acc.w += __shfl_xor(acc.w, mm, 64);
        }
        if (sub == 0) {
            float4 o;
            o.x = fmaxf(acc.x + bv.x, 0.f);
            o.y = fmaxf(acc.y + bv.y, 0.f);
            o.z = fmaxf(acc.z + bv.z, 0.f);
            o.w = fmaxf(acc.w + bv.w, 0.f);
            o4[(size_t)node * 16 + f4] = o;
        }
    }
}

// ---------------------------------------------------------------------------
// Fallback path (standalone gemm + atomic scatter) if ws too small
// ---------------------------------------------------------------------------
__global__ __launch_bounds__(256) void gemm_fallback_kernel(const float* __restrict__ x,
                                                            const float* __restrict__ W,
                                                            unsigned short* __restrict__ hb) {
    __shared__ unsigned short Wt[D_OUT * WSTR];
    const int tid = threadIdx.x;
    for (int i = tid; i < D_IN * D_OUT; i += 256) {
        const int k = i >> 6;
        const int f = i & 63;
        Wt[f * WSTR + k] = f2bf(W[i]);
    }
    __syncthreads();

    const int wave = tid >> 6;
    const int lane = tid & 63;
    const int m    = lane & 15;
    const int quad = lane >> 4;
    const int n0   = blockIdx.x * 64 + wave * 16;

    bf16x8 bfrag[4][4];
    #pragma unroll
    for (int ft = 0; ft < 4; ++ft)
        #pragma unroll
        for (int ks = 0; ks < 4; ++ks)
            bfrag[ft][ks] = *reinterpret_cast<const bf16x8*>(
                &Wt[(ft * 16 + m) * WSTR + ks * 32 + quad * 8]);

    const int nodeA = min(n0 + m, N_NODES - 1);
    const float* xr = x + (size_t)nodeA * D_IN;
    bf16x8 afrag[4];
    #pragma unroll
    for (int ks = 0; ks < 4; ++ks) {
        const float4 u = *reinterpret_cast<const float4*>(xr + ks * 32 + quad * 8);
        const float4 v = *reinterpret_cast<const float4*>(xr + ks * 32 + quad * 8 + 4);
        bf16x8 a;
        a[0] = (short)f2bf(u.x); a[1] = (short)f2bf(u.y);
        a[2] = (short)f2bf(u.z); a[3] = (short)f2bf(u.w);
        a[4] = (short)f2bf(v.x); a[5] = (short)f2bf(v.y);
        a[6] = (short)f2bf(v.z); a[7] = (short)f2bf(v.w);
        afrag[ks] = a;
    }

    f32x4 acc[4];
    #pragma unroll
    for (int ft = 0; ft < 4; ++ft) { acc[ft][0]=0.f; acc[ft][1]=0.f; acc[ft][2]=0.f; acc[ft][3]=0.f; }

    #pragma unroll
    for (int ks = 0; ks < 4; ++ks)
        #pragma unroll
        for (int ft = 0; ft < 4; ++ft)
            acc[ft] = __builtin_amdgcn_mfma_f32_16x16x32_bf16(
                afrag[ks], bfrag[ft][ks], acc[ft], 0, 0, 0);

    #pragma unroll
    for (int r = 0; r < 4; ++r) {
        const int node = n0 + quad * 4 + r;
        if (node < N_NODES) {
            #pragma unroll
            for (int ft = 0; ft < 4; ++ft)
                hb[(size_t)node * D_OUT + ft * 16 + m] = f2bf(acc[ft][r]);
        }
    }
}

__global__ void init_bias_kernel(float* __restrict__ out, const float* __restrict__ b) {
    int i = blockIdx.x * blockDim.x + threadIdx.x;
    const int total4 = N_NODES * (D_OUT / 4);
    if (i < total4) {
        int f4 = i & (D_OUT / 4 - 1);
        reinterpret_cast<float4*>(out)[i] = reinterpret_cast<const float4*>(b)[f4];
    }
}

__global__ void scatter_kernel(const unsigned short* __restrict__ hb, const int* __restrict__ ei,
                               float* __restrict__ out) {
    const long long t = (long long)blockIdx.x * blockDim.x + threadIdx.x;
    const int e = (int)(t >> 6);
    const int f = (int)(t & 63);
    if (e < N_EDGES) {
        atomicAdd(out + (size_t)ei[N_EDGES + e] * D_OUT + f,
                  bf2f(hb[(size_t)ei[e] * D_OUT + f]));
    }
}

__global__ void relu_kernel(float* __restrict__ out) {
    int i = blockIdx.x * blockDim.x + threadIdx.x;
    const int total4 = N_NODES * (D_OUT / 4);
    if (i < total4) {
        float4 v = reinterpret_cast<float4*>(out)[i];
        v.x = fmaxf(v.x, 0.f); v.y = fmaxf(v.y, 0.f);
        v.z = fmaxf(v.z, 0.f); v.w = fmaxf(v.w, 0.f);
        reinterpret_cast<float4*>(out)[i] = v;
    }
}

// ---------------------------------------------------------------------------
extern "C" void kernel_launch(void* const* d_in, const int* in_sizes, int n_in,
                              void* d_out, int out_size, void* d_ws, size_t ws_size,
                              hipStream_t stream) {
    const float* x  = (const float*)d_in[0];
    const int*   ei = (const int*)d_in[1];
    const float* W  = (const float*)d_in[2];
    const float* b  = (const float*)d_in[3];
    float* out = (float*)d_out;
    char*  ws  = (char*)d_ws;

    size_t off = 0;
    auto take = [&](size_t bytes) { size_t p = off; off = (off + bytes + 255) & ~255ULL; return p; };
    const size_t o_h    = take((size_t)N_NODES * D_OUT * sizeof(unsigned short)); // 12.8 MB
    const size_t o_gcur = take((size_t)NBKT * sizeof(int));
    const size_t o_ebuf = take((size_t)NBKT * CAP * sizeof(int));                 // 10.25 MB
    const size_t needed = off;

    unsigned short* hb = (unsigned short*)(ws + o_h);

    if (needed <= ws_size) {
        int* gcur = (int*)(ws + o_gcur);
        int* ebuf = (int*)(ws + o_ebuf);
        hipMemsetAsync(gcur, 0, (size_t)NBKT * sizeof(int), stream);
        fused_gp_kernel<<<PBLK + GBLK, 512, 0, stream>>>(x, W, hb, ei, gcur, ebuf);
        accumulate_kernel<<<NBKT, 1024, 0, stream>>>(hb, gcur, ebuf, b, out);
    } else {
        gemm_fallback_kernel<<<(N_NODES + 63) / 64, 256, 0, stream>>>(x, W, hb);
        const int total4 = N_NODES * (D_OUT / 4);
        init_bias_kernel<<<(total4 + 255) / 256, 256, 0, stream>>>(out, b);
        const long long threads = (long long)N_EDGES * 64;
        scatter_kernel<<<(int)((threads + 255) / 256), 256, 0, stream>>>(hb, ei, out);
        relu_kernel<<<(total4 + 255) / 256, 256, 0, stream>>>(out);
    }
}